// Round 1
// baseline (1271.837 us; speedup 1.0000x reference)
//
#include <hip/hip_runtime.h>
#include <math.h>

// B=8192, D=128, NUM_CLASSES=512, MARGIN=0.2
#define BATCH 8192
#define DIM 128
#define MARGIN_F 0.2f

#define RM 32            // anchor rows per block
#define CN 64            // columns per tile
#define LDA 132          // padded LDS row stride (floats); keeps float4 align, breaks pow2 stride
#define NBLK (BATCH / RM)   // 256 blocks
#define NTILE (BATCH / CN)  // 128 column tiles

// ---------------- kernel 1: L2 normalize rows ----------------
__global__ __launch_bounds__(256) void tl_normalize(const float* __restrict__ emb,
                                                    float* __restrict__ en) {
    int row  = blockIdx.x * 4 + (threadIdx.x >> 6);   // 1 wave per row
    int lane = threadIdx.x & 63;
    float2 v = *reinterpret_cast<const float2*>(emb + (size_t)row * DIM + lane * 2);
    float ss = v.x * v.x + v.y * v.y;
#pragma unroll
    for (int off = 32; off > 0; off >>= 1) ss += __shfl_xor(ss, off);
    float inv = 1.0f / fmaxf(sqrtf(ss), 1e-12f);
    *reinterpret_cast<float2*>(en + (size_t)row * DIM + lane * 2) =
        make_float2(v.x * inv, v.y * inv);
}

// ---------------- kernel 2: fused distance + mining ----------------
__global__ __launch_bounds__(256) void tl_mine(const float* __restrict__ en,
                                               const int* __restrict__ labels,
                                               float* __restrict__ blockSum,
                                               float* __restrict__ blockCnt) {
    __shared__ float As[RM][LDA];
    __shared__ float Bs[CN][LDA];
    __shared__ int   lblA[RM];
    __shared__ int   lblB[CN];
    __shared__ float dapS[RM];
    __shared__ float perS[RM];
    __shared__ float cntS[RM];

    const int tid = threadIdx.x;
    const int tx  = tid & 15;    // column group 0..15
    const int ty  = tid >> 4;    // row group 0..15
    const int rowBase = blockIdx.x * RM;
    const int r0 = ty * 2, r1 = r0 + 1;
    const int gi0 = rowBase + r0, gi1 = rowBase + r1;

    // stage anchor rows (32 x 128 floats) as float4, coalesced
#pragma unroll
    for (int it = 0; it < 4; ++it) {
        int idx = tid + it * 256;        // 0..1023
        int r   = idx >> 5;              // /32
        int c4  = idx & 31;
        float4 v = reinterpret_cast<const float4*>(en + (size_t)(rowBase + r) * DIM)[c4];
        *reinterpret_cast<float4*>(&As[r][c4 * 4]) = v;
    }
    if (tid < RM) lblA[tid] = labels[rowBase + tid];
    __syncthreads();

    const int la0 = lblA[r0], la1 = lblA[r1];

    // ---------- pass 1: hardest positive per anchor row ----------
    float mp0 = -INFINITY, mp1 = -INFINITY;

    for (int ct = 0; ct < NTILE; ++ct) {
        const int colBase = ct * CN;
#pragma unroll
        for (int it = 0; it < 8; ++it) {
            int idx = tid + it * 256;    // 0..2047
            int r   = idx >> 5;
            int c4  = idx & 31;
            float4 v = reinterpret_cast<const float4*>(en + (size_t)(colBase + r) * DIM)[c4];
            *reinterpret_cast<float4*>(&Bs[r][c4 * 4]) = v;
        }
        if (tid < CN) lblB[tid] = labels[colBase + tid];
        __syncthreads();

        float acc[2][4];
#pragma unroll
        for (int r = 0; r < 2; ++r)
#pragma unroll
            for (int c = 0; c < 4; ++c) acc[r][c] = 0.0f;

#pragma unroll 8
        for (int k4 = 0; k4 < DIM / 4; ++k4) {
            float4 a0 = *reinterpret_cast<const float4*>(&As[r0][k4 * 4]);
            float4 a1 = *reinterpret_cast<const float4*>(&As[r1][k4 * 4]);
#pragma unroll
            for (int cc = 0; cc < 4; ++cc) {
                float4 b = *reinterpret_cast<const float4*>(&Bs[tx + 16 * cc][k4 * 4]);
                acc[0][cc] += a0.x * b.x + a0.y * b.y + a0.z * b.z + a0.w * b.w;
                acc[1][cc] += a1.x * b.x + a1.y * b.y + a1.z * b.z + a1.w * b.w;
            }
        }

#pragma unroll
        for (int cc = 0; cc < 4; ++cc) {
            int c  = tx + 16 * cc;
            int j  = colBase + c;
            int lb = lblB[c];
            float d0 = fmaxf(1.0f - acc[0][cc], 0.0f);
            float d1 = fmaxf(1.0f - acc[1][cc], 0.0f);
            if (lb == la0 && j != gi0) mp0 = fmaxf(mp0, d0);
            if (lb == la1 && j != gi1) mp1 = fmaxf(mp1, d1);
        }
        __syncthreads();
    }

    // reduce hardest positive across the 16 column-group threads (lane bits 0..3)
#pragma unroll
    for (int m = 1; m < 16; m <<= 1) {
        mp0 = fmaxf(mp0, __shfl_xor(mp0, m));
        mp1 = fmaxf(mp1, __shfl_xor(mp1, m));
    }
    if (tx == 0) { dapS[r0] = mp0; dapS[r1] = mp1; }
    __syncthreads();

    const float dapRaw0 = dapS[r0], dapRaw1 = dapS[r1];
    const float dap0 = (dapRaw0 == -INFINITY) ? 0.0f : dapRaw0;  // sanitized, as in reference
    const float dap1 = (dapRaw1 == -INFINITY) ? 0.0f : dapRaw1;

    // ---------- pass 2: semi-hard / hardest negative ----------
    float sm0 = INFINITY, sm1 = INFINITY;   // semi-hard min
    float hm0 = INFINITY, hm1 = INFINITY;   // hardest-negative min

    for (int ct = 0; ct < NTILE; ++ct) {
        const int colBase = ct * CN;
#pragma unroll
        for (int it = 0; it < 8; ++it) {
            int idx = tid + it * 256;
            int r   = idx >> 5;
            int c4  = idx & 31;
            float4 v = reinterpret_cast<const float4*>(en + (size_t)(colBase + r) * DIM)[c4];
            *reinterpret_cast<float4*>(&Bs[r][c4 * 4]) = v;
        }
        if (tid < CN) lblB[tid] = labels[colBase + tid];
        __syncthreads();

        float acc[2][4];
#pragma unroll
        for (int r = 0; r < 2; ++r)
#pragma unroll
            for (int c = 0; c < 4; ++c) acc[r][c] = 0.0f;

#pragma unroll 8
        for (int k4 = 0; k4 < DIM / 4; ++k4) {
            float4 a0 = *reinterpret_cast<const float4*>(&As[r0][k4 * 4]);
            float4 a1 = *reinterpret_cast<const float4*>(&As[r1][k4 * 4]);
#pragma unroll
            for (int cc = 0; cc < 4; ++cc) {
                float4 b = *reinterpret_cast<const float4*>(&Bs[tx + 16 * cc][k4 * 4]);
                acc[0][cc] += a0.x * b.x + a0.y * b.y + a0.z * b.z + a0.w * b.w;
                acc[1][cc] += a1.x * b.x + a1.y * b.y + a1.z * b.z + a1.w * b.w;
            }
        }

#pragma unroll
        for (int cc = 0; cc < 4; ++cc) {
            int c  = tx + 16 * cc;
            int lb = lblB[c];
            float d0 = fmaxf(1.0f - acc[0][cc], 0.0f);
            float d1 = fmaxf(1.0f - acc[1][cc], 0.0f);
            if (lb != la0) {
                hm0 = fminf(hm0, d0);
                if (d0 > dap0 && d0 < dap0 + MARGIN_F) sm0 = fminf(sm0, d0);
            }
            if (lb != la1) {
                hm1 = fminf(hm1, d1);
                if (d1 > dap1 && d1 < dap1 + MARGIN_F) sm1 = fminf(sm1, d1);
            }
        }
        __syncthreads();
    }

#pragma unroll
    for (int m = 1; m < 16; m <<= 1) {
        sm0 = fminf(sm0, __shfl_xor(sm0, m));
        sm1 = fminf(sm1, __shfl_xor(sm1, m));
        hm0 = fminf(hm0, __shfl_xor(hm0, m));
        hm1 = fminf(hm1, __shfl_xor(hm1, m));
    }

    if (tx == 0) {
        // row r0
        {
            bool hasPos = (dapRaw0 != -INFINITY);
            bool hasNeg = (hm0 != INFINITY);
            float dan = (sm0 != INFINITY) ? sm0 : hm0;
            float per = 0.0f; float v = 0.0f;
            if (hasPos && hasNeg) { per = fmaxf(dap0 - dan + MARGIN_F, 0.0f); v = 1.0f; }
            perS[r0] = per; cntS[r0] = v;
        }
        // row r1
        {
            bool hasPos = (dapRaw1 != -INFINITY);
            bool hasNeg = (hm1 != INFINITY);
            float dan = (sm1 != INFINITY) ? sm1 : hm1;
            float per = 0.0f; float v = 0.0f;
            if (hasPos && hasNeg) { per = fmaxf(dap1 - dan + MARGIN_F, 0.0f); v = 1.0f; }
            perS[r1] = per; cntS[r1] = v;
        }
    }
    __syncthreads();

    if (tid == 0) {
        float s = 0.0f, c = 0.0f;
#pragma unroll
        for (int r = 0; r < RM; ++r) { s += perS[r]; c += cntS[r]; }
        blockSum[blockIdx.x] = s;
        blockCnt[blockIdx.x] = c;
    }
}

// ---------------- kernel 3: final reduction ----------------
__global__ __launch_bounds__(256) void tl_finalize(const float* __restrict__ blockSum,
                                                   const float* __restrict__ blockCnt,
                                                   float* __restrict__ out) {
    int tid = threadIdx.x;   // 256 threads == NBLK
    float s = blockSum[tid];
    float c = blockCnt[tid];
#pragma unroll
    for (int off = 32; off > 0; off >>= 1) {
        s += __shfl_xor(s, off);
        c += __shfl_xor(c, off);
    }
    __shared__ float ss[4], cs[4];
    if ((tid & 63) == 0) { ss[tid >> 6] = s; cs[tid >> 6] = c; }
    __syncthreads();
    if (tid == 0) {
        float S = ss[0] + ss[1] + ss[2] + ss[3];
        float C = cs[0] + cs[1] + cs[2] + cs[3];
        out[0] = S / fmaxf(C, 1.0f);
    }
}

extern "C" void kernel_launch(void* const* d_in, const int* in_sizes, int n_in,
                              void* d_out, int out_size, void* d_ws, size_t ws_size,
                              hipStream_t stream) {
    const float* emb    = (const float*)d_in[0];
    const int*   labels = (const int*)d_in[1];
    float*       out    = (float*)d_out;

    float* en  = (float*)d_ws;                 // 8192*128 floats = 4 MB
    float* bs  = en + (size_t)BATCH * DIM;     // 256 floats
    float* bc  = bs + NBLK;                    // 256 floats

    tl_normalize<<<BATCH / 4, 256, 0, stream>>>(emb, en);
    tl_mine<<<NBLK, 256, 0, stream>>>(en, labels, bs, bc);
    tl_finalize<<<1, 256, 0, stream>>>(bs, bc, out);
}

// Round 3
// 70.480 us; speedup vs baseline: 18.0453x; 18.0453x over previous
//
#include <hip/hip_runtime.h>
#include <math.h>

// B=8192, D=128, NUM_CLASSES=512, MARGIN=0.2
#define BATCH 8192
#define DIM 128
#define MARGIN_F 0.2f
#define NCLS 512
#define MAXMEM 128       // max stored members per class (~16 expected)

#define NCHUNK 8         // column chunks for pass 2
#define CHW 1024         // cols per chunk
#define BT 64            // cols per staged B-tile (64*256B = 16 KB per buffer)
#define NT (CHW / BT)    // tiles per chunk = 16

typedef _Float16 f16x8 __attribute__((ext_vector_type(8)));
typedef _Float16 f16x2 __attribute__((ext_vector_type(2)));
typedef float    f32x4 __attribute__((ext_vector_type(4)));

// ---------------- K1: normalize rows -> fp16 pre-swizzled pack + inv norms ----------------
__global__ __launch_bounds__(256) void tl_prep(const float* __restrict__ emb,
                                               unsigned short* __restrict__ eP16,
                                               float* __restrict__ invn,
                                               int* __restrict__ ccnt) {
    if (blockIdx.x == 0) {
        for (int i = threadIdx.x; i < NCLS; i += 256) ccnt[i] = 0;
    }
    int row  = blockIdx.x * 4 + (threadIdx.x >> 6);
    int l    = threadIdx.x & 63;
    float2 v = *reinterpret_cast<const float2*>(emb + (size_t)row * DIM + l * 2);
    float ss = v.x * v.x + v.y * v.y;
#pragma unroll
    for (int o = 32; o > 0; o >>= 1) ss += __shfl_xor(ss, o);
    float inv = 1.0f / fmaxf(sqrtf(ss), 1e-12f);
    if (l == 0) invn[row] = inv;
    f16x2 h;
    h[0] = (_Float16)(v.x * inv);
    h[1] = (_Float16)(v.y * inv);
    // pre-swizzle: 16B chunk c of row goes to chunk c ^ (row&7)
    int c   = l >> 2;                               // 16B chunk index 0..15
    int off = ((c ^ (row & 7)) * 16) + (l & 3) * 4; // byte offset in row
    *reinterpret_cast<f16x2*>((char*)eP16 + (size_t)row * 256 + off) = h;
}

// ---------------- K2: build class member lists ----------------
__global__ __launch_bounds__(256) void tl_lists(const int* __restrict__ labels,
                                                int* __restrict__ ccnt,
                                                int* __restrict__ mem) {
    int t   = blockIdx.x * 256 + threadIdx.x;
    int lbl = labels[t];
    int idx = atomicAdd(&ccnt[lbl], 1);
    if (idx < MAXMEM) mem[lbl * MAXMEM + idx] = t;
}

// ---------------- K3: hardest positive per row (fp32 gather over classmates) ----------------
__global__ __launch_bounds__(256) void tl_dap(const float* __restrict__ emb,
                                              const int* __restrict__ labels,
                                              const float* __restrict__ invn,
                                              const int* __restrict__ ccnt,
                                              const int* __restrict__ mem,
                                              float* __restrict__ dapA) {
    int row = blockIdx.x * 4 + (threadIdx.x >> 6);
    int l   = threadIdx.x & 63;
    float2 a = *reinterpret_cast<const float2*>(emb + (size_t)row * DIM + l * 2);
    int   lbl = labels[row];
    int   c   = min(ccnt[lbl], MAXMEM);
    float ia  = invn[row];
    float mind = INFINITY;
    bool  found = false;
    for (int m = 0; m < c; ++m) {
        int j = mem[lbl * MAXMEM + m];
        if (j == row) continue;
        float2 b = *reinterpret_cast<const float2*>(emb + (size_t)j * DIM + l * 2);
        float p = a.x * b.x + a.y * b.y;
#pragma unroll
        for (int o = 32; o > 0; o >>= 1) p += __shfl_xor(p, o);
        float dot = p * ia * invn[j];
        mind = fminf(mind, dot);
        found = true;
    }
    if (l == 0) dapA[row] = found ? fmaxf(1.0f - mind, 0.0f) : -INFINITY;
}

// ---------------- K4: pass-2 mining via fp16 MFMA ----------------
__device__ __forceinline__ void stageB(const char* __restrict__ gtile, char* lds, int tid) {
    int wid = tid >> 6, lane = tid & 63;
#pragma unroll
    for (int i = 0; i < 4; ++i) {
        int off = i * 4096 + wid * 1024;   // wave-uniform LDS offset; HW adds lane*16
        __builtin_amdgcn_global_load_lds(
            (const __attribute__((address_space(1))) unsigned int*)(gtile + off + lane * 16),
            (__attribute__((address_space(3))) unsigned int*)(lds + off),
            16, 0, 0);
    }
}

__global__ __launch_bounds__(256, 2) void tl_mine2(const unsigned short* __restrict__ eP16,
                                                   const int* __restrict__ labels,
                                                   const float* __restrict__ dapA,
                                                   float* __restrict__ part) {
    __shared__ char  Bs[2][BT * 256];    // 64 rows x 256 B, double-buffered = 32 KB
    __shared__ float mkS[2][128];

    const int tid = threadIdx.x;
    const int l   = tid & 63;
    const int wid = tid >> 6;
    const int wr  = wid >> 1, wc = wid & 1;   // 2x2 wave grid; wave tile 64 rows x 32 cols
    const int rb  = blockIdx.x >> 3;
    const int ch  = blockIdx.x & (NCHUNK - 1);
    const int rowBase = rb * 128;
    const int colBase = ch * CHW;
    const char* eP = (const char*)eP16;

    const int lo   = l & 15;    // operand row/col within 16
    const int kgrp = l >> 4;    // k-slice group 0..3
    const int swz  = lo & 7;

    // A fragments held in registers: 64 rows x K=128
    f16x8 af[4][4];
#pragma unroll
    for (int rf = 0; rf < 4; ++rf)
#pragma unroll
        for (int kc = 0; kc < 4; ++kc) {
            int row   = rowBase + wr * 64 + rf * 16 + lo;
            int chunk = (kc * 4 + kgrp) ^ swz;
            af[rf][kc] = *reinterpret_cast<const f16x8*>(eP + (size_t)row * 256 + chunk * 16);
        }

    // per-row data: rows rf*16 + kgrp*4 + i (C/D layout: col=lane&15, row=(lane>>4)*4+reg)
    float wHi[16]; int la[16]; float mk[16];
#pragma unroll
    for (int rf = 0; rf < 4; ++rf)
#pragma unroll
        for (int i = 0; i < 4; ++i) {
            int r = rowBase + wr * 64 + rf * 16 + kgrp * 4 + i;
            float draw = dapA[r];
            float ds   = (draw > -1e30f) ? draw : 0.0f;    // sanitized d_ap
            wHi[rf * 4 + i] = 1.0f - ds;                   // dot upper bound (dist > dap)
            la[rf * 4 + i]  = labels[r];
            mk[rf * 4 + i]  = -INFINITY;
        }

    stageB(eP + (size_t)colBase * 256, Bs[0], tid);
    __syncthreads();

    int cur = 0;
    for (int t = 0; t < NT; ++t) {
        if (t + 1 < NT) stageB(eP + (size_t)(colBase + (t + 1) * BT) * 256, Bs[cur ^ 1], tid);

        f32x4 acc[4][2];
#pragma unroll
        for (int rf = 0; rf < 4; ++rf)
#pragma unroll
            for (int cf = 0; cf < 2; ++cf) {
                acc[rf][cf][0] = 0.0f; acc[rf][cf][1] = 0.0f;
                acc[rf][cf][2] = 0.0f; acc[rf][cf][3] = 0.0f;
            }

#pragma unroll
        for (int kc = 0; kc < 4; ++kc) {
            f16x8 bf[2];
#pragma unroll
            for (int cf = 0; cf < 2; ++cf) {
                int rr    = wc * 32 + cf * 16 + lo;          // tile-local output col (0..63)
                int chunk = (kc * 4 + kgrp) ^ (rr & 7);
                bf[cf] = *reinterpret_cast<const f16x8*>(&Bs[cur][rr * 256 + chunk * 16]);
            }
#pragma unroll
            for (int rf = 0; rf < 4; ++rf)
#pragma unroll
                for (int cf = 0; cf < 2; ++cf)
                    acc[rf][cf] = __builtin_amdgcn_mfma_f32_16x16x32_f16(
                        af[rf][kc], bf[cf], acc[rf][cf], 0, 0, 0);
        }

        // epilogue: fused semi-hard/hard mining in dot space
        int lbB[2];
#pragma unroll
        for (int cf = 0; cf < 2; ++cf)
            lbB[cf] = labels[colBase + t * BT + wc * 32 + cf * 16 + lo];
#pragma unroll
        for (int rf = 0; rf < 4; ++rf)
#pragma unroll
            for (int cf = 0; cf < 2; ++cf)
#pragma unroll
                for (int i = 0; i < 4; ++i) {
                    float dot = acc[rf][cf][i];
                    float hi  = wHi[rf * 4 + i];
                    bool  win = (dot < hi) && (dot + MARGIN_F > hi);
                    float key = win ? dot : dot - 4.0f;
                    key = (lbB[cf] != la[rf * 4 + i]) ? key : -INFINITY;
                    mk[rf * 4 + i] = fmaxf(mk[rf * 4 + i], key);
                }
        __syncthreads();
        cur ^= 1;
    }

    // reduce across the 16 lanes sharing the same rows (lane bits 0..3)
#pragma unroll
    for (int m = 1; m < 16; m <<= 1)
#pragma unroll
        for (int r16 = 0; r16 < 16; ++r16)
            mk[r16] = fmaxf(mk[r16], __shfl_xor(mk[r16], m));
    if ((l & 15) == 0) {
#pragma unroll
        for (int rf = 0; rf < 4; ++rf)
#pragma unroll
            for (int i = 0; i < 4; ++i)
                mkS[wc][wr * 64 + rf * 16 + kgrp * 4 + i] = mk[rf * 4 + i];
    }
    __syncthreads();
    if (tid < 128)
        part[(size_t)ch * BATCH + rowBase + tid] = fmaxf(mkS[0][tid], mkS[1][tid]);
}

// ---------------- K5: finalize ----------------
__global__ __launch_bounds__(1024) void tl_fin(const float* __restrict__ dapA,
                                               const float* __restrict__ part,
                                               float* __restrict__ out) {
    int tid = threadIdx.x;
    float s = 0.0f, c = 0.0f;
    for (int r = tid; r < BATCH; r += 1024) {
        float draw = dapA[r];
        float mkv  = part[r];
#pragma unroll
        for (int ch = 1; ch < NCHUNK; ++ch) mkv = fmaxf(mkv, part[(size_t)ch * BATCH + r]);
        bool hasPos = draw > -1e30f;
        bool hasNeg = mkv > -1e30f;
        float dap   = hasPos ? draw : 0.0f;
        bool  semi  = mkv > -2.0f;                 // in-window keys > -1.2; out-window < -2.9
        float dotAn = semi ? mkv : mkv + 4.0f;
        float dan   = fmaxf(1.0f - dotAn, 0.0f);
        if (hasPos && hasNeg) {
            s += fmaxf(dap - dan + MARGIN_F, 0.0f);
            c += 1.0f;
        }
    }
#pragma unroll
    for (int o = 32; o > 0; o >>= 1) { s += __shfl_xor(s, o); c += __shfl_xor(c, o); }
    __shared__ float ssum[16], scnt[16];
    int w = tid >> 6;
    if ((tid & 63) == 0) { ssum[w] = s; scnt[w] = c; }
    __syncthreads();
    if (tid == 0) {
        float S = 0.0f, C = 0.0f;
#pragma unroll
        for (int i = 0; i < 16; ++i) { S += ssum[i]; C += scnt[i]; }
        out[0] = S / fmaxf(C, 1.0f);
    }
}

extern "C" void kernel_launch(void* const* d_in, const int* in_sizes, int n_in,
                              void* d_out, int out_size, void* d_ws, size_t ws_size,
                              hipStream_t stream) {
    const float* emb    = (const float*)d_in[0];
    const int*   labels = (const int*)d_in[1];
    float*       out    = (float*)d_out;

    char* ws = (char*)d_ws;
    unsigned short* eP16 = (unsigned short*)(ws);                    // 2 MB
    float* invn = (float*)(ws + 2 * 1024 * 1024);                    // 32 KB
    float* dapA = (float*)(ws + 2 * 1024 * 1024 + 32 * 1024);        // 32 KB
    float* part = (float*)(ws + 2 * 1024 * 1024 + 64 * 1024);        // 256 KB
    int*   ccnt = (int*)(ws + 2 * 1024 * 1024 + 320 * 1024);         // 2 KB
    int*   cmem = (int*)(ws + 2 * 1024 * 1024 + 324 * 1024);         // 256 KB

    tl_prep <<<BATCH / 4, 256, 0, stream>>>(emb, eP16, invn, ccnt);
    tl_lists<<<BATCH / 256, 256, 0, stream>>>(labels, ccnt, cmem);
    tl_dap  <<<BATCH / 4, 256, 0, stream>>>(emb, labels, invn, ccnt, cmem, dapA);
    tl_mine2<<<(BATCH / 128) * NCHUNK, 256, 0, stream>>>(eP16, labels, dapA, part);
    tl_fin  <<<1, 1024, 0, stream>>>(dapA, part, out);
}